// Round 4
// baseline (643.474 us; speedup 1.0000x reference)
//
#include <hip/hip_runtime.h>

// LIF neuron scan: N=4096 independent neurons, T=8192 strictly-sequential steps.
// One thread per neuron; 64 blocks x 64 threads = 64 waves, ~1 per CU.
// Regime: per-neuron dependency chain, balanced against single-wave VALU issue
// (1 instr / 2 cy). Both ~28 cy/step by the accounting in the session journal.
//
// Numerics: every reference-visible rounding uses _rn intrinsics in the
// reference's exact order (no FMA contraction). Divisions use the Markstein
// 2-FMA sequence with a correctly-rounded hoisted reciprocal (provably RN(a/b)
// for normal operands -- all operands here are comfortably normal), keeping
// results bit-exact vs the NumPy reference while off-loading the chain.
//
// Chain layout (7 dependent ops/step):
//   cndmask(a) -> add(u) -> mul(q) -> fma(e) -> fma(q') -> add(vi) -> cmp
// 'a' carries RN(v_rest - v); its two candidate next values (const a_rst, or
// RN(v_rest - vi)) are computed in parallel with the threshold compare.
//
// Refractory: integer end-time encoding. Reference decrements a float counter
// and tests >0, which yields exactly ceil(refr_set) in-refractory steps after
// a spike (spikes impossible while refractory). inr = (t < refr_end);
// refr_end = sp ? t+1+n_refr : refr_end. 2 VALU vs 4 in the float version.

#define N_NEURONS 4096
#define T_STEPS   8192
#define BN        64                    // 1 wavefront per block
#define TILE_T4   8                     // float4 groups per time tile
#define TILE_T    (TILE_T4 * 4)         // 32 steps per tile
#define NTILES    (T_STEPS / TILE_T)    // 256 (even -> clean ping-pong pairs)

__device__ __forceinline__ float div_rn_fast(float a, float b, float rb) {
    // rb = RN(1/b), b normal; returns RN(a/b) for normal a,b,quotient (Markstein).
    const float q = __fmul_rn(a, rb);
    const float e = __fmaf_rn(-b, q, a);
    return __fmaf_rn(e, rb, q);
}

__global__ __launch_bounds__(BN)
void lif_main(const float* __restrict__ I,
              const float* __restrict__ p_tau,
              const float* __restrict__ p_vth,
              const float* __restrict__ p_vreset,
              const float* __restrict__ p_rm,
              const float* __restrict__ p_vrest,
              const float* __restrict__ p_refr,
              float* __restrict__ out)
{
    const int lane = threadIdx.x;
    const int n    = blockIdx.x * BN + lane;

    const float tau_m    = p_tau[0];
    const float v_th     = p_vth[0];
    const float v_rst    = p_vreset[0];
    const float r_m      = p_rm[0];
    const float v_rest   = p_vrest[0];
    const float refr_set = __fdiv_rn(p_refr[0], 1.0f);   // refractory / DT (DT=1)
    const int   n_refr   = (int)ceilf(refr_set);         // in-refr steps per spike

    const float rcp_tau = __fdiv_rn(1.0f, tau_m);        // RN(1/tau)
    const float rcp_1k  = __fdiv_rn(1.0f, 1000.0f);      // RN(1/1000)
    const float a_rst   = __fsub_rn(v_rest, v_rst);      // RN(v_rest - v_reset)

    float v        = v_rest;                    // v[0] = v_rest
    float a        = __fsub_rn(v_rest, v_rest); // RN(v_rest - v[0]) = 0 exactly
    int   refr_end = 0;                         // inr iff t < refr_end
    float prev     = 0.0f;                      // prev spike; 0 seeds out[:,0]=0

    const float4* rowI4 = reinterpret_cast<const float4*>(I   + (size_t)n * T_STEPS);
    float4*       rowO4 = reinterpret_cast<float4*>      (out + (size_t)n * T_STEPS);

    float4 bufA[TILE_T4], bufB[TILE_T4];

    #pragma unroll
    for (int c = 0; c < TILE_T4; ++c) bufA[c] = rowI4[c];   // tile 0

    auto compute_tile = [&](const float4* __restrict__ buf, int tile) {
        #pragma unroll
        for (int t4 = 0; t4 < TILE_T4; ++t4) {
            const float4 x  = buf[t4];
            const int    c0 = tile * TILE_T + 4 * t4;

            // w = r_m * RN(I/1000), both roundings per reference; off the chain
            const float w0 = __fmul_rn(r_m, div_rn_fast(x.x, 1000.0f, rcp_1k));
            const float w1 = __fmul_rn(r_m, div_rn_fast(x.y, 1000.0f, rcp_1k));
            const float w2 = __fmul_rn(r_m, div_rn_fast(x.z, 1000.0f, rcp_1k));
            const float w3 = __fmul_rn(r_m, div_rn_fast(x.w, 1000.0f, rcp_1k));

            float4 s;
            s.x = prev;   // spike of step c0-1 -> out col c0 (col 0 gets the seed)

            #pragma unroll
            for (int k = 0; k < 4; ++k) {
                const int t = c0 + k;            // uniform scalar step index
                float spf = 0.0f;
                if (t < T_STEPS - 1) {           // steps 0..8190 (uniform guard)
                    const float w   = (k == 0) ? w0 : (k == 1) ? w1 : (k == 2) ? w2 : w3;
                    const bool  inr = t < refr_end;              // v_cmp_lt_i32
                    const float u   = __fadd_rn(a, w);           // RN(a + w)
                    const float dv  = div_rn_fast(u, tau_m, rcp_tau); // RN(u/tau)
                    const float vi  = __fadd_rn(v, dv);
                    const bool  cross = vi >= v_th;
                    const bool  rst   = inr || cross;            // SALU mask op
                    const float a_ch  = __fsub_rn(v_rest, vi);   // parallel w/ cmp
                    v = rst ? v_rst : vi;                        // parallel selects
                    a = rst ? a_rst : a_ch;
                    const bool sp = (!inr) && cross;             // SALU mask op
                    refr_end = sp ? (t + 1 + n_refr) : refr_end; // 1 cndmask
                    spf = sp ? 1.0f : 0.0f;
                }
                if      (k == 0) s.y = spf;
                else if (k == 1) s.z = spf;
                else if (k == 2) s.w = spf;
                else             prev = spf;
            }
            rowO4[c0 / 4] = s;   // cols c0 .. c0+3
        }
    };

    // ping-pong over tile pairs: no register copy between tiles
    for (int p = 0; p < NTILES / 2; ++p) {
        const int tA = 2 * p, tB = 2 * p + 1;
        #pragma unroll
        for (int c = 0; c < TILE_T4; ++c)            // prefetch tile 2p+1
            bufB[c] = rowI4[tB * TILE_T4 + c];
        compute_tile(bufA, tA);
        if (tB + 1 < NTILES) {
            #pragma unroll
            for (int c = 0; c < TILE_T4; ++c)        // prefetch tile 2p+2
                bufA[c] = rowI4[(tB + 1) * TILE_T4 + c];
        }
        compute_tile(bufB, tB);
    }
}

extern "C" void kernel_launch(void* const* d_in, const int* in_sizes, int n_in,
                              void* d_out, int out_size, void* d_ws, size_t ws_size,
                              hipStream_t stream)
{
    lif_main<<<dim3(N_NEURONS / BN), dim3(BN), 0, stream>>>(
        (const float*)d_in[0],   // I_input
        (const float*)d_in[1],   // tau_m
        (const float*)d_in[2],   // v_th
        (const float*)d_in[3],   // v_reset
        (const float*)d_in[4],   // r_m
        (const float*)d_in[5],   // v_rest
        (const float*)d_in[6],   // refractory
        (float*)d_out);
}